// Round 11
// baseline (149.325 us; speedup 1.0000x reference)
//
#include <hip/hip_runtime.h>
#include <hip/hip_bf16.h>
#include <float.h>

#define EPSV 1e-6f
#define TGT_TILE 1024      // targets per block tile (SoA floats = 8 KB LDS)
#define SRC_TILE 1024      // src points per block
#define WAVES 8            // 512 threads
#define SPT 16             // src points per lane (1024 / 64)

typedef float f32x2 __attribute__((ext_vector_type(2)));
typedef float f32x4 __attribute__((ext_vector_type(4)));

// Phase A: directed partial Hausdorff (squared), expansion form, packed fp32:
//   |s'-t|^2 = |s'|^2 + (|t|^2 - 2 s'.t),   s' = s + eps
// SPT=16: each broadcast ds_read_b128 pair (4 targets, SoA xs/ys) feeds 16
// src points -> DS/CU ~2.6us vs VALU/SIMD ~5.3us: VALU clearly dominant,
// DS queueing off the critical path (rounds 3->4, 8 showed amortization is
// the lever). Depth-2 register prefetch covers LDS latency. All per-lane
// state compile-time indexed (no scratch; round-7 lesson). launch_bounds
// (512,1) gives the allocator 256 VGPR headroom (1 block/CU regardless).
// Cross-wave min via LDS; plain stores to ws. No atomics, deterministic.
__global__ __launch_bounds__(512, 1) void hausdorff_partial_kernel(
    const float* __restrict__ c1, const float* __restrict__ c2,
    float* __restrict__ ws, int L1, int L2, int STmax, int TTmax, int Lmax) {

    const int b   = blockIdx.y;
    const int B   = gridDim.y;
    const int dir = blockIdx.z;
    const int st  = blockIdx.x % STmax;
    const int tt  = blockIdx.x / STmax;

    const float* src; const float* tgt; int Lsrc, Ltgt;
    if (dir == 0) { src = c2 + (size_t)b * L2 * 2; tgt = c1 + (size_t)b * L1 * 2; Lsrc = L2; Ltgt = L1; }
    else          { src = c1 + (size_t)b * L1 * 2; tgt = c2 + (size_t)b * L2 * 2; Lsrc = L1; Ltgt = L2; }

    const int srcBase = st * SRC_TILE;
    const int tgtBase = tt * TGT_TILE;
    if (srcBase >= Lsrc || tgtBase >= Ltgt) return;   // uniform

    const int lane = threadIdx.x & 63;
    const int w    = threadIdx.x >> 6;

    __shared__ f32x4 xs4[TGT_TILE / 4 + 1];     // SoA target x (+1: prefetch overread)
    __shared__ f32x4 ys4[TGT_TILE / 4 + 1];     // SoA target y
    __shared__ float red[WAVES][SRC_TILE];      // 32 KB
    __shared__ float s2s[SRC_TILE];             // 4 KB
    float* xsf = (float*)xs4;
    float* ysf = (float*)ys4;

    // This lane's 16 src points (identical across waves). Compile-time
    // indexed only (full unroll) -> registers, no scratch.
    f32x2 nsx2[SPT], nsy2[SPT];
    float s2v[SPT];
    #pragma unroll
    for (int s = 0; s < SPT; ++s) {
        const int j = srcBase + s * 64 + lane;
        if (j < Lsrc) {
            float2 p = ((const float2*)src)[j];
            float sx = p.x + EPSV, sy = p.y + EPSV;
            float nx = -2.0f * sx, ny = -2.0f * sy;
            nsx2[s] = (f32x2){nx, nx};
            nsy2[s] = (f32x2){ny, ny};
            s2v[s]  = fmaf(sx, sx, sy * sy);
        } else {
            nsx2[s] = (f32x2){0.f, 0.f};
            nsy2[s] = (f32x2){0.f, 0.f};
            s2v[s]  = -FLT_MAX;   // phase B never reads j >= Lsrc
        }
    }

    // Stage this block's target tile, SoA; pad to a multiple of 4 with dups.
    const int chunk = min(TGT_TILE, Ltgt - tgtBase);
    const float2* tg = (const float2*)tgt + tgtBase;
    for (int t = threadIdx.x; t < chunk; t += 512) {
        float2 p = tg[t];
        xsf[t] = p.x;
        ysf[t] = p.y;
    }
    const int padded = (chunk + 3) & ~3;
    if ((int)threadIdx.x < padded - chunk) {
        float2 p = tg[chunk - 1];               // dup pad (min-neutral)
        xsf[chunk + threadIdx.x] = p.x;
        ysf[chunk + threadIdx.x] = p.y;
    }
    __syncthreads();

    float mm[SPT];
    #pragma unroll
    for (int s = 0; s < SPT; ++s) mm[s] = FLT_MAX;

    const int P4   = padded >> 2;            // 4-target groups
    const int pbeg = (w * P4) >> 3;
    const int pend = ((w + 1) * P4) >> 3;

#define PROC(xv, yv) {                                                        \
        f32x2 xa_ = __builtin_shufflevector((xv), (xv), 0, 1);                \
        f32x2 xb_ = __builtin_shufflevector((xv), (xv), 2, 3);                \
        f32x2 ya_ = __builtin_shufflevector((yv), (yv), 0, 1);                \
        f32x2 yb_ = __builtin_shufflevector((yv), (yv), 2, 3);                \
        f32x2 t2a = __builtin_elementwise_fma(ya_, ya_, xa_ * xa_);           \
        f32x2 t2b = __builtin_elementwise_fma(yb_, yb_, xb_ * xb_);           \
        _Pragma("unroll")                                                     \
        for (int s = 0; s < SPT; ++s) {                                       \
            f32x2 da = __builtin_elementwise_fma(xa_, nsx2[s],                \
                           __builtin_elementwise_fma(ya_, nsy2[s], t2a));     \
            f32x2 db = __builtin_elementwise_fma(xb_, nsx2[s],                \
                           __builtin_elementwise_fma(yb_, nsy2[s], t2b));     \
            mm[s] = fminf(fminf(mm[s], da.x), da.y);  /* -> v_min3_f32 */     \
            mm[s] = fminf(fminf(mm[s], db.x), db.y);                          \
        } }

    if (pbeg < pend) {
        // depth-2 software pipeline: loads lead computation by 2 slots
        f32x4 xa = xs4[pbeg + 0], ya = ys4[pbeg + 0];
        f32x4 xb = xs4[pbeg + 1], yb = ys4[pbeg + 1];   // garbage ok if unused
        int i = pbeg;
        for (; i + 2 < pend; i += 2) {
            f32x4 xc = xs4[i + 2], yc = ys4[i + 2];
            f32x4 xd = xs4[i + 3], yd = ys4[i + 3];
            PROC(xa, ya)
            PROC(xb, yb)
            xa = xc; ya = yc; xb = xd; yb = yd;
        }
        PROC(xa, ya)
        if (i + 1 < pend) { PROC(xb, yb) }
    }
#undef PROC

    // publish per-wave partial mins (+ s2 once)
    #pragma unroll
    for (int s = 0; s < SPT; ++s)
        red[w][s * 64 + lane] = mm[s];
    if (w == 0) {
        #pragma unroll
        for (int s = 0; s < SPT; ++s)
            s2s[s * 64 + lane] = s2v[s];
    }
    __syncthreads();

    // combine across waves; each thread owns 2 srcs; plain stores
    for (int t = threadIdx.x; t < SRC_TILE; t += 512) {
        float m = red[0][t];
        #pragma unroll
        for (int ww = 1; ww < WAVES; ++ww)
            m = fminf(m, red[ww][t]);
        const size_t idx = ((size_t)((dir * B + b) * TTmax + tt)) * (size_t)Lmax
                           + (size_t)srcBase + t;
        ws[idx] = s2s[t] + m;
    }
}

// Phase B: per batch, min over tgt-tiles per src, max over srcs and both
// directions, sqrt, scale by resolution. float4 loads where aligned.
__global__ __launch_bounds__(512) void hausdorff_reduce_kernel(
    const float* __restrict__ ws, const float* __restrict__ res,
    float* __restrict__ out, int L1, int L2, int TTmax, int Lmax, int B) {

    const int b = blockIdx.x;
    float vmax = 0.0f;   // also serves as the >=0 clamp

    for (int dir = 0; dir < 2; ++dir) {
        const int Lsrc = (dir == 0) ? L2 : L1;
        const int Ltgt = (dir == 0) ? L1 : L2;
        const int nt   = (Ltgt + TGT_TILE - 1) / TGT_TILE;
        const float* base = ws + ((size_t)(dir * B + b) * TTmax) * (size_t)Lmax;

        if ((Lmax & 3) == 0) {                    // 16B-aligned fast path
            const int n4 = Lsrc >> 2;
            for (int j = threadIdx.x; j < n4; j += 512) {
                float4 m4 = ((const float4*)base)[j];
                for (int t = 1; t < nt; ++t) {
                    float4 v = ((const float4*)(base + (size_t)t * Lmax))[j];
                    m4.x = fminf(m4.x, v.x); m4.y = fminf(m4.y, v.y);
                    m4.z = fminf(m4.z, v.z); m4.w = fminf(m4.w, v.w);
                }
                vmax = fmaxf(vmax,
                             fmaxf(fmaxf(m4.x, m4.y), fmaxf(m4.z, m4.w)));
            }
            for (int j = (n4 << 2) + threadIdx.x; j < Lsrc; j += 512) {
                float m = base[j];
                for (int t = 1; t < nt; ++t)
                    m = fminf(m, base[(size_t)t * Lmax + j]);
                vmax = fmaxf(vmax, m);
            }
        } else {
            for (int j = threadIdx.x; j < Lsrc; j += 512) {
                float m = base[j];
                for (int t = 1; t < nt; ++t)
                    m = fminf(m, base[(size_t)t * Lmax + j]);
                vmax = fmaxf(vmax, m);
            }
        }
    }

    for (int off = 32; off > 0; off >>= 1)
        vmax = fmaxf(vmax, __shfl_down(vmax, off));

    __shared__ float r[8];
    const int lane = threadIdx.x & 63, w = threadIdx.x >> 6;
    if (lane == 0) r[w] = vmax;
    __syncthreads();
    if (threadIdx.x == 0) {
        float m = r[0];
        #pragma unroll
        for (int i = 1; i < 8; ++i) m = fmaxf(m, r[i]);
        out[b] = sqrtf(fmaxf(m, 0.0f)) * res[b];
    }
}

extern "C" void kernel_launch(void* const* d_in, const int* in_sizes, int n_in,
                              void* d_out, int out_size, void* d_ws, size_t ws_size,
                              hipStream_t stream) {
    const float* c1  = (const float*)d_in[0];
    const float* c2  = (const float*)d_in[1];
    const float* res = (const float*)d_in[2];
    float* out = (float*)d_out;

    const int B  = in_sizes[2];
    const int L1 = in_sizes[0] / (B * 2);
    const int L2 = in_sizes[1] / (B * 2);

    float* ws = (float*)d_ws;

    const int Lmax  = max(L1, L2);
    const int STmax = (Lmax + SRC_TILE - 1) / SRC_TILE;
    const int TTmax = (Lmax + TGT_TILE - 1) / TGT_TILE;

    dim3 gridA(STmax * TTmax, B, 2);
    hipLaunchKernelGGL(hausdorff_partial_kernel, gridA, dim3(512), 0, stream,
                       c1, c2, ws, L1, L2, STmax, TTmax, Lmax);

    hipLaunchKernelGGL(hausdorff_reduce_kernel, dim3(B), dim3(512), 0, stream,
                       ws, res, out, L1, L2, TTmax, Lmax, B);
}

// Round 12
// 28.625 us; speedup vs baseline: 5.2166x; 5.2166x over previous
//
#include <hip/hip_runtime.h>
#include <hip/hip_bf16.h>
#include <float.h>

#define EPSV 1e-6f
#define TGT_TILE 1024      // targets per block tile (AoS float4 = 8 KB LDS)
#define SRC_TILE 1024      // src points per block
#define WAVES 8            // 512 threads
#define SPT 16             // src points per lane (1024 / 64) — SCALAR state

// Phase A: directed partial Hausdorff (squared), expansion form, SCALAR math:
//   |s'-t|^2 = |s'|^2 + (|t|^2 - 2 s'.t),   s' = s + eps
// SPT=16 scalar: each broadcast ds_read_b128 (2 targets, AoS float4) feeds 16
// srcs -> DS pipe ~29% of VALU: VALU cleanly dominant (pipes were near-
// balanced at SPT=8, capping issue at ~45%). NO pk math: v_pk_fma_f32 takes
// ~4cyc/wave64 (2x work/lane) so pk = scalar in cycles but doubles splat
// register pressure (r7/r11 spills). Scalar state = 64 floats/lane ~ fits.
// Depth-2 register prefetch covers LDS latency (r10, +2us). All per-lane
// state compile-time indexed. Cross-wave min via LDS; plain stores. No atomics.
__global__ __launch_bounds__(512, 1) void hausdorff_partial_kernel(
    const float* __restrict__ c1, const float* __restrict__ c2,
    float* __restrict__ ws, int L1, int L2, int STmax, int TTmax, int Lmax) {

    const int b   = blockIdx.y;
    const int B   = gridDim.y;
    const int dir = blockIdx.z;
    const int st  = blockIdx.x % STmax;
    const int tt  = blockIdx.x / STmax;

    const float* src; const float* tgt; int Lsrc, Ltgt;
    if (dir == 0) { src = c2 + (size_t)b * L2 * 2; tgt = c1 + (size_t)b * L1 * 2; Lsrc = L2; Ltgt = L1; }
    else          { src = c1 + (size_t)b * L1 * 2; tgt = c2 + (size_t)b * L2 * 2; Lsrc = L1; Ltgt = L2; }

    const int srcBase = st * SRC_TILE;
    const int tgtBase = tt * TGT_TILE;
    if (srcBase >= Lsrc || tgtBase >= Ltgt) return;   // uniform

    const int lane = threadIdx.x & 63;
    const int w    = threadIdx.x >> 6;

    __shared__ float4 t_lds[TGT_TILE / 2 + 1];  // 2 targets/slot (+1: prefetch overread)
    __shared__ float  red[WAVES][SRC_TILE];     // 32 KB
    __shared__ float  s2s[SRC_TILE];            // 4 KB

    // This lane's 16 src points (identical across waves), scalar registers,
    // compile-time indexed only (full unroll).
    float nsx[SPT], nsy[SPT], s2v[SPT];
    #pragma unroll
    for (int s = 0; s < SPT; ++s) {
        const int j = srcBase + s * 64 + lane;
        if (j < Lsrc) {
            float2 p = ((const float2*)src)[j];
            float sx = p.x + EPSV, sy = p.y + EPSV;
            nsx[s] = -2.0f * sx;
            nsy[s] = -2.0f * sy;
            s2v[s] = fmaf(sx, sx, sy * sy);
        } else {
            nsx[s] = 0.f; nsy[s] = 0.f;
            s2v[s] = -FLT_MAX;   // phase B never reads j >= Lsrc
        }
    }

    // Stage this block's target tile (raw float2, AoS).
    const int chunk = min(TGT_TILE, Ltgt - tgtBase);
    const float2* tg = (const float2*)tgt + tgtBase;
    for (int t = threadIdx.x; t < chunk; t += 512) {
        ((float2*)t_lds)[t] = tg[t];
    }
    if (threadIdx.x == 0 && (chunk & 1)) {
        ((float2*)t_lds)[chunk] = tg[chunk - 1];   // dup pad (min-neutral)
    }
    __syncthreads();

    float mm[SPT];
    #pragma unroll
    for (int s = 0; s < SPT; ++s) mm[s] = FLT_MAX;

    const int P    = (chunk + 1) >> 1;       // float4 slots
    const int pbeg = (w * P) >> 3;
    const int pend = ((w + 1) * P) >> 3;

#define PROC(a) {                                                          \
        float t2a = fmaf((a).y, (a).y, (a).x * (a).x);                     \
        float t2b = fmaf((a).w, (a).w, (a).z * (a).z);                     \
        _Pragma("unroll")                                                  \
        for (int s = 0; s < SPT; ++s) {                                    \
            float da = fmaf((a).x, nsx[s], fmaf((a).y, nsy[s], t2a));      \
            float db = fmaf((a).z, nsx[s], fmaf((a).w, nsy[s], t2b));      \
            mm[s] = fminf(fminf(mm[s], da), db);  /* -> v_min3_f32 */      \
        } }

    if (pbeg < pend) {
        // depth-2 software pipeline: loads lead computation by 2 slots
        float4 a0 = t_lds[pbeg + 0];
        float4 a1 = t_lds[pbeg + 1];    // may overread (pad slot); unused then
        int i = pbeg;
        for (; i + 2 < pend; i += 2) {
            float4 a2 = t_lds[i + 2];
            float4 a3 = t_lds[i + 3];
            PROC(a0)
            PROC(a1)
            a0 = a2; a1 = a3;
        }
        PROC(a0)
        if (i + 1 < pend) { PROC(a1) }
    }
#undef PROC

    // publish per-wave partial mins (+ s2 once)
    #pragma unroll
    for (int s = 0; s < SPT; ++s)
        red[w][s * 64 + lane] = mm[s];
    if (w == 0) {
        #pragma unroll
        for (int s = 0; s < SPT; ++s)
            s2s[s * 64 + lane] = s2v[s];
    }
    __syncthreads();

    // combine across waves; each thread owns 2 srcs; plain stores
    for (int t = threadIdx.x; t < SRC_TILE; t += 512) {
        float m = red[0][t];
        #pragma unroll
        for (int ww = 1; ww < WAVES; ++ww)
            m = fminf(m, red[ww][t]);
        const size_t idx = ((size_t)((dir * B + b) * TTmax + tt)) * (size_t)Lmax
                           + (size_t)srcBase + t;
        ws[idx] = s2s[t] + m;
    }
}

// Phase B: per batch, min over tgt-tiles per src, max over srcs and both
// directions, sqrt, scale by resolution. float4 loads where aligned.
__global__ __launch_bounds__(512) void hausdorff_reduce_kernel(
    const float* __restrict__ ws, const float* __restrict__ res,
    float* __restrict__ out, int L1, int L2, int TTmax, int Lmax, int B) {

    const int b = blockIdx.x;
    float vmax = 0.0f;   // also serves as the >=0 clamp

    for (int dir = 0; dir < 2; ++dir) {
        const int Lsrc = (dir == 0) ? L2 : L1;
        const int Ltgt = (dir == 0) ? L1 : L2;
        const int nt   = (Ltgt + TGT_TILE - 1) / TGT_TILE;
        const float* base = ws + ((size_t)(dir * B + b) * TTmax) * (size_t)Lmax;

        if ((Lmax & 3) == 0) {                    // 16B-aligned fast path
            const int n4 = Lsrc >> 2;
            for (int j = threadIdx.x; j < n4; j += 512) {
                float4 m4 = ((const float4*)base)[j];
                for (int t = 1; t < nt; ++t) {
                    float4 v = ((const float4*)(base + (size_t)t * Lmax))[j];
                    m4.x = fminf(m4.x, v.x); m4.y = fminf(m4.y, v.y);
                    m4.z = fminf(m4.z, v.z); m4.w = fminf(m4.w, v.w);
                }
                vmax = fmaxf(vmax,
                             fmaxf(fmaxf(m4.x, m4.y), fmaxf(m4.z, m4.w)));
            }
            for (int j = (n4 << 2) + threadIdx.x; j < Lsrc; j += 512) {
                float m = base[j];
                for (int t = 1; t < nt; ++t)
                    m = fminf(m, base[(size_t)t * Lmax + j]);
                vmax = fmaxf(vmax, m);
            }
        } else {
            for (int j = threadIdx.x; j < Lsrc; j += 512) {
                float m = base[j];
                for (int t = 1; t < nt; ++t)
                    m = fminf(m, base[(size_t)t * Lmax + j]);
                vmax = fmaxf(vmax, m);
            }
        }
    }

    for (int off = 32; off > 0; off >>= 1)
        vmax = fmaxf(vmax, __shfl_down(vmax, off));

    __shared__ float r[8];
    const int lane = threadIdx.x & 63, w = threadIdx.x >> 6;
    if (lane == 0) r[w] = vmax;
    __syncthreads();
    if (threadIdx.x == 0) {
        float m = r[0];
        #pragma unroll
        for (int i = 1; i < 8; ++i) m = fmaxf(m, r[i]);
        out[b] = sqrtf(fmaxf(m, 0.0f)) * res[b];
    }
}

extern "C" void kernel_launch(void* const* d_in, const int* in_sizes, int n_in,
                              void* d_out, int out_size, void* d_ws, size_t ws_size,
                              hipStream_t stream) {
    const float* c1  = (const float*)d_in[0];
    const float* c2  = (const float*)d_in[1];
    const float* res = (const float*)d_in[2];
    float* out = (float*)d_out;

    const int B  = in_sizes[2];
    const int L1 = in_sizes[0] / (B * 2);
    const int L2 = in_sizes[1] / (B * 2);

    float* ws = (float*)d_ws;

    const int Lmax  = max(L1, L2);
    const int STmax = (Lmax + SRC_TILE - 1) / SRC_TILE;
    const int TTmax = (Lmax + TGT_TILE - 1) / TGT_TILE;

    dim3 gridA(STmax * TTmax, B, 2);
    hipLaunchKernelGGL(hausdorff_partial_kernel, gridA, dim3(512), 0, stream,
                       c1, c2, ws, L1, L2, STmax, TTmax, Lmax);

    hipLaunchKernelGGL(hausdorff_reduce_kernel, dim3(B), dim3(512), 0, stream,
                       ws, res, out, L1, L2, TTmax, Lmax, B);
}

// Round 13
// 23.312 us; speedup vs baseline: 6.4055x; 1.2279x over previous
//
#include <hip/hip_runtime.h>
#include <hip/hip_bf16.h>
#include <float.h>

#define EPSV 1e-6f
#define SRC_BLK 256        // srcs per block = 16 fragments x 16 cols
#define NFRAG 16
#define LT_MAX 4096        // targets staged per super-tile (64 KB LDS)
#define WAVES 8            // 512 threads

typedef float  f32x4_t  __attribute__((ext_vector_type(4)));
typedef short  bf16x8_t __attribute__((ext_vector_type(8)));
typedef unsigned short u16;
typedef u16    u16x8    __attribute__((ext_vector_type(8)));

__device__ __forceinline__ u16 bf_hi(float v) {
    return __bfloat16_as_ushort(__float2bfloat16(v));   // RNE
}
__device__ __forceinline__ float bf_f(u16 u) {
    return __bfloat162float(__ushort_as_bfloat16(u));
}

// Phase A: directed Hausdorff via MFMA. Per (dir,b,src-block of 256):
//   dot(A_row(tgt), B_col(src)) = t2 - 2 s'.t   (K=8 bf16 hi/lo slots)
//   A (targets, rows): [txh, txl, txh, tyh, tyl, tyh, t2h, t2l]
//   B (srcs, cols):    [-2sxh, -2sxh, -2sxl, -2syh, -2syh, -2syl, 1, 1]
// D = A.B via mfma_f32_16x16x32_bf16: lane holds col(src)=lane&15, 4 tgt rows
// -> 2 min3 per MFMA; per-src min across row-groups via shfl_xor(16,32).
// B-side k>=8 lanes are ZERO (zslot) so A-side k>=8 garbage contributes 0.
// Block output: max over its 256 srcs of (s2 + min), plain store to ws.
__global__ __launch_bounds__(512, 1) void hausdorff_mfma_kernel(
    const float* __restrict__ c1, const float* __restrict__ c2,
    float* __restrict__ ws, int L1, int L2, int STmax) {

    const int b   = blockIdx.y;
    const int B   = gridDim.y;
    const int dir = blockIdx.z;
    const int st  = blockIdx.x;

    const float* src; const float* tgt; int Lsrc, Ltgt;
    if (dir == 0) { src = c2 + (size_t)b * L2 * 2; tgt = c1 + (size_t)b * L1 * 2; Lsrc = L2; Ltgt = L1; }
    else          { src = c1 + (size_t)b * L1 * 2; tgt = c2 + (size_t)b * L2 * 2; Lsrc = L1; Ltgt = L2; }

    const int srcBase = st * SRC_BLK;
    if (srcBase >= Lsrc) return;   // finalize never reads these ws entries

    const int lane = threadIdx.x & 63;
    const int w    = threadIdx.x >> 6;

    __shared__ u16x8 Tform[LT_MAX];           // 64 KB
    __shared__ u16x8 Sform[SRC_BLK];          // 4 KB
    __shared__ u16x8 zslot;                   // 16 B of zeros
    __shared__ float s2s[SRC_BLK];            // 1 KB
    __shared__ float red[WAVES][SRC_BLK];     // 8 KB
    __shared__ float rmax[4];

    // ---- stage S-form (threads 0..255) + zslot ----
    if (threadIdx.x < SRC_BLK) {
        const int j = srcBase + threadIdx.x;
        float sx = 0.f, sy = 0.f;
        const bool ok = (j < Lsrc);
        if (ok) {
            float2 p = ((const float2*)src)[j];
            sx = p.x + EPSV; sy = p.y + EPSV;
        }
        const float nx = -2.0f * sx, ny = -2.0f * sy;
        const u16 nxh = bf_hi(nx); const u16 nxl = bf_hi(nx - bf_f(nxh));
        const u16 nyh = bf_hi(ny); const u16 nyl = bf_hi(ny - bf_f(nyh));
        const u16 one = bf_hi(1.0f);
        u16x8 r;
        r[0] = nxh; r[1] = nxh; r[2] = nxl;
        r[3] = nyh; r[4] = nyh; r[5] = nyl;
        r[6] = one; r[7] = one;
        Sform[threadIdx.x] = r;
        s2s[threadIdx.x] = ok ? fmaf(sx, sx, sy * sy) : -FLT_MAX;
    }
    if (threadIdx.x == 256) {
        zslot = (u16x8){0, 0, 0, 0, 0, 0, 0, 0};
    }
    __syncthreads();

    // ---- load this wave's 16 src fragments (kept in registers) ----
    bf16x8_t bfrag[NFRAG];
    #pragma unroll
    for (int f = 0; f < NFRAG; ++f) {
        const bf16x8_t* bp = (lane < 16)
            ? &((const bf16x8_t*)Sform)[f * 16 + lane]
            : (const bf16x8_t*)&zslot;
        bfrag[f] = *bp;
    }

    float mm[NFRAG];
    #pragma unroll
    for (int f = 0; f < NFRAG; ++f) mm[f] = FLT_MAX;

    const f32x4_t zacc = {0.f, 0.f, 0.f, 0.f};
    const u16 padhi = bf_hi(1e30f);

    // ---- target super-tiles ----
    for (int tbase = 0; tbase < Ltgt; tbase += LT_MAX) {
        const int chunk  = min(LT_MAX, Ltgt - tbase);
        const int padded = (chunk + 15) & ~15;

        for (int e = threadIdx.x; e < padded; e += 512) {
            u16x8 r;
            if (e < chunk) {
                float2 p = ((const float2*)tgt)[tbase + e];
                const float t2 = fmaf(p.y, p.y, p.x * p.x);
                const u16 txh = bf_hi(p.x); const u16 txl = bf_hi(p.x - bf_f(txh));
                const u16 tyh = bf_hi(p.y); const u16 tyl = bf_hi(p.y - bf_f(tyh));
                const u16 t2h = bf_hi(t2);  const u16 t2l = bf_hi(t2 - bf_f(t2h));
                r[0] = txh; r[1] = txl; r[2] = txh;
                r[3] = tyh; r[4] = tyl; r[5] = tyh;
                r[6] = t2h; r[7] = t2l;
            } else {
                r = (u16x8){0, 0, 0, 0, 0, 0, 0, 0};
                r[6] = padhi;                 // dot = 1e30 -> never the min
            }
            Tform[e] = r;
        }
        __syncthreads();

        const int ntile = padded >> 4;
        const int tbeg  = (w * ntile) >> 3;
        const int tend  = ((w + 1) * ntile) >> 3;

        if (tbeg < tend) {
            const bf16x8_t* Ap = (const bf16x8_t*)Tform;
            bf16x8_t af = Ap[tbeg * 16 + (lane & 15)];
            for (int t = tbeg; t < tend; ++t) {
                const int tn = (t + 1 < tend) ? t + 1 : t;
                bf16x8_t afn = Ap[tn * 16 + (lane & 15)];   // depth-1 prefetch
                #pragma unroll
                for (int f = 0; f < NFRAG; ++f) {
                    f32x4_t acc = __builtin_amdgcn_mfma_f32_16x16x32_bf16(
                        af, bfrag[f], zacc, 0, 0, 0);
                    mm[f] = fminf(fminf(mm[f], acc[0]), acc[1]);  // v_min3
                    mm[f] = fminf(fminf(mm[f], acc[2]), acc[3]);
                }
                af = afn;
            }
        }
        __syncthreads();   // before next super-tile overwrites Tform
    }

    // ---- per-src min across the 4 row-groups, publish per wave ----
    #pragma unroll
    for (int f = 0; f < NFRAG; ++f) {
        float v = mm[f];
        v = fminf(v, __shfl_xor(v, 16));
        v = fminf(v, __shfl_xor(v, 32));
        if (lane < 16) red[w][f * 16 + lane] = v;
    }
    __syncthreads();

    // ---- combine waves, add s2, block max, one plain store ----
    const int t = threadIdx.x;
    float v = 0.f;
    if (t < SRC_BLK) {
        float m = red[0][t];
        #pragma unroll
        for (int ww = 1; ww < WAVES; ++ww) m = fminf(m, red[ww][t]);
        v = fmaxf(s2s[t] + m, 0.f);
    }
    for (int off = 32; off > 0; off >>= 1)
        v = fmaxf(v, __shfl_down(v, off));
    if (t < 256 && lane == 0) rmax[t >> 6] = v;
    __syncthreads();
    if (t == 0) {
        ws[(size_t)(dir * B + b) * STmax + st] =
            fmaxf(fmaxf(rmax[0], rmax[1]), fmaxf(rmax[2], rmax[3]));
    }
}

// Phase B: per batch, max over the two directions' block maxima, sqrt, scale.
__global__ void hausdorff_finalize_kernel(
    const float* __restrict__ ws, const float* __restrict__ res,
    float* __restrict__ out, int STmax, int nst0, int nst1, int B) {

    const int b = blockIdx.x;
    const int lane = threadIdx.x;
    float v = 0.f;
    for (int i = lane; i < nst0 + nst1; i += 64) {
        v = fmaxf(v, (i < nst0) ? ws[(size_t)(0 * B + b) * STmax + i]
                                : ws[(size_t)(1 * B + b) * STmax + (i - nst0)]);
    }
    for (int off = 32; off > 0; off >>= 1)
        v = fmaxf(v, __shfl_down(v, off));
    if (lane == 0) out[b] = sqrtf(v) * res[b];
}

extern "C" void kernel_launch(void* const* d_in, const int* in_sizes, int n_in,
                              void* d_out, int out_size, void* d_ws, size_t ws_size,
                              hipStream_t stream) {
    const float* c1  = (const float*)d_in[0];
    const float* c2  = (const float*)d_in[1];
    const float* res = (const float*)d_in[2];
    float* out = (float*)d_out;

    const int B  = in_sizes[2];
    const int L1 = in_sizes[0] / (B * 2);
    const int L2 = in_sizes[1] / (B * 2);

    float* ws = (float*)d_ws;

    const int Lmax  = max(L1, L2);
    const int STmax = (Lmax + SRC_BLK - 1) / SRC_BLK;
    const int nst0  = (L2 + SRC_BLK - 1) / SRC_BLK;   // dir0: src = c2
    const int nst1  = (L1 + SRC_BLK - 1) / SRC_BLK;   // dir1: src = c1

    dim3 gridA(STmax, B, 2);
    hipLaunchKernelGGL(hausdorff_mfma_kernel, gridA, dim3(512), 0, stream,
                       c1, c2, ws, L1, L2, STmax);

    hipLaunchKernelGGL(hausdorff_finalize_kernel, dim3(B), dim3(64), 0, stream,
                       ws, res, out, STmax, nst0, nst1, B);
}